// Round 1
// baseline (399.354 us; speedup 1.0000x reference)
//
#include <hip/hip_runtime.h>

#define EPS 1e-8f
#define BETA 0.8f

typedef __attribute__((ext_vector_type(8))) short bf16x8;
typedef __attribute__((ext_vector_type(4))) float f32x4;
typedef __attribute__((ext_vector_type(4))) float float4v;
typedef __attribute__((ext_vector_type(4))) unsigned short ushort4v;

__device__ __forceinline__ unsigned short f2b(float f) {
  unsigned int u = __builtin_bit_cast(unsigned int, f);
  u += 0x7fffu + ((u >> 16) & 1u);
  return (unsigned short)(u >> 16);
}

// ---------------------------------------------------------------------------
// K1: At(bf16) = A + 0.8*S ; dis[row] = 1/sqrt(rowsum + EPS)
// One block per row, 256 threads, float4 loads.
// ---------------------------------------------------------------------------
__global__ __launch_bounds__(256) void k_degree_convert(
    const float* __restrict__ A, const float* __restrict__ S,
    unsigned short* __restrict__ At, float* __restrict__ dis) {
  const int row = blockIdx.x;
  const int tid = threadIdx.x;
  const size_t base = (size_t)row * 8192;
  float sum = 0.f;
#pragma unroll
  for (int it = 0; it < 8; ++it) {
    const int c = it * 1024 + tid * 4;
    float4v a = *reinterpret_cast<const float4v*>(A + base + c);
    float4v s = *reinterpret_cast<const float4v*>(S + base + c);
    float v0 = a.x + BETA * s.x;
    float v1 = a.y + BETA * s.y;
    float v2 = a.z + BETA * s.z;
    float v3 = a.w + BETA * s.w;
    sum += (v0 + v1) + (v2 + v3);
    ushort4v o = {f2b(v0), f2b(v1), f2b(v2), f2b(v3)};
    *reinterpret_cast<ushort4v*>(At + base + c) = o;
  }
#pragma unroll
  for (int off = 32; off > 0; off >>= 1) sum += __shfl_xor(sum, off, 64);
  __shared__ float wsum[4];
  if ((tid & 63) == 0) wsum[tid >> 6] = sum;
  __syncthreads();
  if (tid == 0) {
    float d = ((wsum[0] + wsum[1]) + (wsum[2] + wsum[3])) + EPS;
    dis[row] = (d > 0.f) ? 1.0f / sqrtf(d) : 0.f;
  }
}

// ---------------------------------------------------------------------------
// elementwise f32 -> bf16 (vectorized)
// ---------------------------------------------------------------------------
__global__ __launch_bounds__(256) void k_conv_bf16(
    const float* __restrict__ in, unsigned short* __restrict__ out, int n4) {
  int idx = blockIdx.x * 256 + threadIdx.x;
  if (idx >= n4) return;
  float4v v = reinterpret_cast<const float4v*>(in)[idx];
  ushort4v o = {f2b(v.x), f2b(v.y), f2b(v.z), f2b(v.w)};
  reinterpret_cast<ushort4v*>(out)[idx] = o;
}

// W[R][C] f32 -> WT[C][R] bf16 (tiny matrices, coalescing unimportant)
__global__ __launch_bounds__(256) void k_convT(
    const float* __restrict__ W, unsigned short* __restrict__ WT, int R, int C) {
  int idx = blockIdx.x * 256 + threadIdx.x;
  if (idx >= R * C) return;
  int r = idx / C, c = idx - r * C;
  WT[c * R + r] = f2b(W[idx]);
}

// ---------------------------------------------------------------------------
// C = A[M][K](bf16) @ BT[N][K](bf16)^T, K-loop BK=64, 4 waves (2x2),
// MFMA 16x16x32. Epilogues:
//   EPI==0: outb[col*M + row] = bf16(dis[row]*acc)          (transposed store)
//   EPI==1: outb[row*N + col] = bf16(relu(dis[row]*acc+b))  (h)
//   EPI==2: outf[row*N + col] = dis[row]*acc + b            (final out)
// ---------------------------------------------------------------------------
template <int BM, int BN, int EPI>
__global__ __launch_bounds__(256) void k_gemm_bt(
    const unsigned short* __restrict__ Ag,   // [M][K]
    const unsigned short* __restrict__ BTg,  // [N][K]
    int M, int N, int K,
    const float* __restrict__ dis,
    const float* __restrict__ bias,
    float* __restrict__ outf,
    unsigned short* __restrict__ outb) {
  constexpr int WM = BM / 2, WN = BN / 2;
  constexpr int MF = WM / 16, NF = WN / 16;
  __shared__ unsigned short Als[BM][64];
  __shared__ unsigned short Bls[BN][64];
  const int tid = threadIdx.x;
  const int lane = tid & 63;
  const int wm = (tid >> 6) >> 1, wn = (tid >> 6) & 1;
  const int brow = blockIdx.x * BM, bcol = blockIdx.y * BN;
  const int ar = tid >> 3;         // 0..31 (row within 32-row staging slab)
  const int ac = (tid & 7) * 8;    // element col within 64-wide K-slab
  const int l15 = lane & 15, lk = (lane >> 4) * 8;

  f32x4 acc[MF][NF];
#pragma unroll
  for (int i = 0; i < MF; ++i)
#pragma unroll
    for (int j = 0; j < NF; ++j) acc[i][j] = (f32x4){0.f, 0.f, 0.f, 0.f};

  for (int k0 = 0; k0 < K; k0 += 64) {
#pragma unroll
    for (int i = 0; i < BM / 32; ++i) {
      const unsigned short* g = Ag + (size_t)(brow + i * 32 + ar) * K + k0 + ac;
      __builtin_amdgcn_global_load_lds(
          (const __attribute__((address_space(1))) void*)g,
          (__attribute__((address_space(3))) void*)&Als[i * 32 + ar][ac], 16, 0, 0);
    }
#pragma unroll
    for (int i = 0; i < BN / 32; ++i) {
      const unsigned short* g = BTg + (size_t)(bcol + i * 32 + ar) * K + k0 + ac;
      __builtin_amdgcn_global_load_lds(
          (const __attribute__((address_space(1))) void*)g,
          (__attribute__((address_space(3))) void*)&Bls[i * 32 + ar][ac], 16, 0, 0);
    }
    __syncthreads();
#pragma unroll
    for (int kk = 0; kk < 2; ++kk) {
      bf16x8 afr[MF], bfr[NF];
#pragma unroll
      for (int mi = 0; mi < MF; ++mi)
        afr[mi] = *reinterpret_cast<const bf16x8*>(
            &Als[wm * WM + mi * 16 + l15][kk * 32 + lk]);
#pragma unroll
      for (int ni = 0; ni < NF; ++ni)
        bfr[ni] = *reinterpret_cast<const bf16x8*>(
            &Bls[wn * WN + ni * 16 + l15][kk * 32 + lk]);
#pragma unroll
      for (int mi = 0; mi < MF; ++mi)
#pragma unroll
        for (int ni = 0; ni < NF; ++ni)
          acc[mi][ni] = __builtin_amdgcn_mfma_f32_16x16x32_bf16(
              afr[mi], bfr[ni], acc[mi][ni], 0, 0, 0);
    }
    __syncthreads();
  }

  const int crow0 = brow + wm * WM, ccol0 = bcol + wn * WN;
#pragma unroll
  for (int mi = 0; mi < MF; ++mi) {
    const int row0 = crow0 + mi * 16 + (lane >> 4) * 4;
    const float d0 = dis[row0], d1 = dis[row0 + 1], d2 = dis[row0 + 2],
                d3 = dis[row0 + 3];
#pragma unroll
    for (int ni = 0; ni < NF; ++ni) {
      const int col = ccol0 + ni * 16 + l15;
      f32x4 a = acc[mi][ni];
      if constexpr (EPI == 0) {
        ushort4v o = {f2b(d0 * a.x), f2b(d1 * a.y), f2b(d2 * a.z),
                      f2b(d3 * a.w)};
        *reinterpret_cast<ushort4v*>(outb + (size_t)col * M + row0) = o;
      } else if constexpr (EPI == 1) {
        const float bb = bias[col];
        float v0 = d0 * a.x + bb; v0 = v0 > 0.f ? v0 : 0.f;
        float v1 = d1 * a.y + bb; v1 = v1 > 0.f ? v1 : 0.f;
        float v2 = d2 * a.z + bb; v2 = v2 > 0.f ? v2 : 0.f;
        float v3 = d3 * a.w + bb; v3 = v3 > 0.f ? v3 : 0.f;
        outb[(size_t)(row0 + 0) * N + col] = f2b(v0);
        outb[(size_t)(row0 + 1) * N + col] = f2b(v1);
        outb[(size_t)(row0 + 2) * N + col] = f2b(v2);
        outb[(size_t)(row0 + 3) * N + col] = f2b(v3);
      } else {
        const float bb = bias[col];
        outf[(size_t)(row0 + 0) * N + col] = d0 * a.x + bb;
        outf[(size_t)(row0 + 1) * N + col] = d1 * a.y + bb;
        outf[(size_t)(row0 + 2) * N + col] = d2 * a.z + bb;
        outf[(size_t)(row0 + 3) * N + col] = d3 * a.w + bb;
      }
    }
  }
}

// ---------------------------------------------------------------------------
extern "C" void kernel_launch(void* const* d_in, const int* in_sizes, int n_in,
                              void* d_out, int out_size, void* d_ws,
                              size_t ws_size, hipStream_t stream) {
  const float* A  = (const float*)d_in[0];
  const float* S  = (const float*)d_in[1];
  const float* x  = (const float*)d_in[2];
  const float* W1 = (const float*)d_in[3];
  const float* b1 = (const float*)d_in[4];
  const float* W2 = (const float*)d_in[5];
  const float* b2 = (const float*)d_in[6];
  float* out = (float*)d_out;

  char* ws = (char*)d_ws;
  unsigned short* At  = (unsigned short*)(ws);                // 128 MB
  unsigned short* xb  = (unsigned short*)(ws + 134217728);    // 8 MB
  unsigned short* M1T = (unsigned short*)(ws + 142606336);    // 4 MB [256][8192]
  unsigned short* hb  = (unsigned short*)(ws + 146800640);    // 4 MB [8192][256]
  unsigned short* M2T = (unsigned short*)(ws + 150994944);    // 2 MB [128][8192]
  unsigned short* W1T = (unsigned short*)(ws + 153092096);    // 256 KB [256][512]
  unsigned short* W2T = (unsigned short*)(ws + 153354240);    // 64 KB [128][256]
  float* dis          = (float*)(ws + 153419776);             // 32 KB

  dim3 blk(256);

  // 1. degree + bf16 conversion of A_tilde
  k_degree_convert<<<8192, blk, 0, stream>>>(A, S, At, dis);
  // 2. operand conversions
  k_conv_bf16<<<4096, blk, 0, stream>>>(x, xb, 4194304 / 4);
  k_convT<<<512, blk, 0, stream>>>(W1, W1T, 512, 256);
  k_convT<<<128, blk, 0, stream>>>(W2, W2T, 256, 128);
  // 3. M1^T = (dis ⊙ (x @ W1))^T              [256][8192]
  k_gemm_bt<128, 64, 0><<<dim3(64, 4), blk, 0, stream>>>(
      xb, W1T, 8192, 256, 512, dis, nullptr, nullptr, M1T);
  // 4. h = relu(dis ⊙ (At @ M1) + b1)         [8192][256] bf16
  k_gemm_bt<128, 64, 1><<<dim3(64, 4), blk, 0, stream>>>(
      At, M1T, 8192, 256, 8192, dis, b1, nullptr, hb);
  // 5. M2^T = (dis ⊙ (h @ W2))^T              [128][8192]
  k_gemm_bt<64, 64, 0><<<dim3(128, 2), blk, 0, stream>>>(
      hb, W2T, 8192, 128, 256, dis, nullptr, nullptr, M2T);
  // 6. out = dis ⊙ (At @ M2) + b2             [8192][128] f32
  k_gemm_bt<64, 64, 2><<<dim3(128, 2), blk, 0, stream>>>(
      At, M2T, 8192, 128, 8192, dis, b2, out, nullptr);
}

// Round 2
// 334.033 us; speedup vs baseline: 1.1956x; 1.1956x over previous
//
#include <hip/hip_runtime.h>

#define EPS 1e-8f
#define BETA 0.8f

typedef __attribute__((ext_vector_type(8))) short bf16x8;
typedef __attribute__((ext_vector_type(4))) float f32x4;
typedef __attribute__((ext_vector_type(4))) float float4v;
typedef __attribute__((ext_vector_type(4))) unsigned short ushort4v;

__device__ __forceinline__ unsigned short f2b(float f) {
  unsigned int u = __builtin_bit_cast(unsigned int, f);
  u += 0x7fffu + ((u >> 16) & 1u);
  return (unsigned short)(u >> 16);
}

// ---------------------------------------------------------------------------
// K1: At(bf16) = A + 0.8*S ; dis[row] = 1/sqrt(rowsum + EPS)
// One block per row, 256 threads. 16 nontemporal float4 loads in flight
// (A,S are read-once streams; keep them out of L3 so At stays resident).
// ---------------------------------------------------------------------------
__global__ __launch_bounds__(256) void k_degree_convert(
    const float* __restrict__ A, const float* __restrict__ S,
    unsigned short* __restrict__ At, float* __restrict__ dis) {
  const int row = blockIdx.x;
  const int tid = threadIdx.x;
  const size_t base = (size_t)row * 8192;
  float sum = 0.f;
#pragma unroll
  for (int h = 0; h < 2; ++h) {
    float4v a[4], s[4];
#pragma unroll
    for (int i = 0; i < 4; ++i) {
      const int c = (h * 4 + i) * 1024 + tid * 4;
      a[i] = __builtin_nontemporal_load(
          reinterpret_cast<const float4v*>(A + base + c));
      s[i] = __builtin_nontemporal_load(
          reinterpret_cast<const float4v*>(S + base + c));
    }
#pragma unroll
    for (int i = 0; i < 4; ++i) {
      const int c = (h * 4 + i) * 1024 + tid * 4;
      float v0 = a[i].x + BETA * s[i].x;
      float v1 = a[i].y + BETA * s[i].y;
      float v2 = a[i].z + BETA * s[i].z;
      float v3 = a[i].w + BETA * s[i].w;
      sum += (v0 + v1) + (v2 + v3);
      ushort4v o = {f2b(v0), f2b(v1), f2b(v2), f2b(v3)};
      *reinterpret_cast<ushort4v*>(At + base + c) = o;
    }
  }
#pragma unroll
  for (int off = 32; off > 0; off >>= 1) sum += __shfl_xor(sum, off, 64);
  __shared__ float wsum[4];
  if ((tid & 63) == 0) wsum[tid >> 6] = sum;
  __syncthreads();
  if (tid == 0) {
    float d = ((wsum[0] + wsum[1]) + (wsum[2] + wsum[3])) + EPS;
    dis[row] = (d > 0.f) ? 1.0f / sqrtf(d) : 0.f;
  }
}

// ---------------------------------------------------------------------------
__global__ __launch_bounds__(256) void k_conv_bf16(
    const float* __restrict__ in, unsigned short* __restrict__ out, int n4) {
  int idx = blockIdx.x * 256 + threadIdx.x;
  if (idx >= n4) return;
  float4v v = reinterpret_cast<const float4v*>(in)[idx];
  ushort4v o = {f2b(v.x), f2b(v.y), f2b(v.z), f2b(v.w)};
  reinterpret_cast<ushort4v*>(out)[idx] = o;
}

__global__ __launch_bounds__(256) void k_convT(
    const float* __restrict__ W, unsigned short* __restrict__ WT, int R, int C) {
  int idx = blockIdx.x * 256 + threadIdx.x;
  if (idx >= R * C) return;
  int r = idx / C, c = idx - r * C;
  WT[c * R + r] = f2b(W[idx]);
}

// ---------------------------------------------------------------------------
// C = A[M][K](bf16) @ BT[N][K](bf16)^T, BK=64, 4 waves (2x2), MFMA 16x16x32.
// Double-buffered LDS, counted vmcnt, raw s_barrier (T3/T4 2-phase minimum).
// Epilogues: 0 = bf16 transposed (dis*acc), 1 = bf16 relu(dis*acc+b),
//            2 = f32 dis*acc+b.
// ---------------------------------------------------------------------------
template <int BM, int BN, int EPI>
__global__ __launch_bounds__(256) void k_gemm_bt(
    const unsigned short* __restrict__ Ag,   // [M][K]
    const unsigned short* __restrict__ BTg,  // [N][K]
    int M, int N, int K,
    const float* __restrict__ dis,
    const float* __restrict__ bias,
    float* __restrict__ outf,
    unsigned short* __restrict__ outb) {
  constexpr int WM = BM / 2, WN = BN / 2;
  constexpr int MF = WM / 16, NF = WN / 16;
  constexpr int NLOADS = BM / 32 + BN / 32;  // per-thread global_load_lds per stage
  __shared__ unsigned short Als[2][BM][64];
  __shared__ unsigned short Bls[2][BN][64];
  const int tid = threadIdx.x;
  const int lane = tid & 63;
  const int wm = (tid >> 6) >> 1, wn = (tid >> 6) & 1;
  const int brow = blockIdx.x * BM, bcol = blockIdx.y * BN;
  const int ar = tid >> 3;       // 0..31
  const int ac = (tid & 7) * 8;  // element col in 64-wide K-slab
  const int l15 = lane & 15, lk = (lane >> 4) * 8;

  f32x4 acc[MF][NF];
#pragma unroll
  for (int i = 0; i < MF; ++i)
#pragma unroll
    for (int j = 0; j < NF; ++j) acc[i][j] = (f32x4){0.f, 0.f, 0.f, 0.f};

  auto stage = [&](int buf, int k0) {
#pragma unroll
    for (int i = 0; i < BM / 32; ++i) {
      const unsigned short* g = Ag + (size_t)(brow + i * 32 + ar) * K + k0 + ac;
      __builtin_amdgcn_global_load_lds(
          (const __attribute__((address_space(1))) void*)g,
          (__attribute__((address_space(3))) void*)&Als[buf][i * 32 + ar][ac],
          16, 0, 0);
    }
#pragma unroll
    for (int i = 0; i < BN / 32; ++i) {
      const unsigned short* g = BTg + (size_t)(bcol + i * 32 + ar) * K + k0 + ac;
      __builtin_amdgcn_global_load_lds(
          (const __attribute__((address_space(1))) void*)g,
          (__attribute__((address_space(3))) void*)&Bls[buf][i * 32 + ar][ac],
          16, 0, 0);
    }
  };

  const int nsteps = K / 64;
  stage(0, 0);
  for (int t = 0; t < nsteps; ++t) {
    const int cur = t & 1;
    if (t + 1 < nsteps) {
      stage(cur ^ 1, (t + 1) * 64);  // prefetch next K-tile into other buffer
      asm volatile("s_waitcnt vmcnt(%0)" ::"n"(NLOADS));  // my cur loads done
    } else {
      asm volatile("s_waitcnt vmcnt(0)");
    }
    __builtin_amdgcn_s_barrier();  // everyone's cur loads landed in LDS
    asm volatile("" ::: "memory");
#pragma unroll
    for (int kk = 0; kk < 2; ++kk) {
      bf16x8 afr[MF], bfr[NF];
#pragma unroll
      for (int mi = 0; mi < MF; ++mi)
        afr[mi] = *reinterpret_cast<const bf16x8*>(
            &Als[cur][wm * WM + mi * 16 + l15][kk * 32 + lk]);
#pragma unroll
      for (int ni = 0; ni < NF; ++ni)
        bfr[ni] = *reinterpret_cast<const bf16x8*>(
            &Bls[cur][wn * WN + ni * 16 + l15][kk * 32 + lk]);
#pragma unroll
      for (int mi = 0; mi < MF; ++mi)
#pragma unroll
        for (int ni = 0; ni < NF; ++ni)
          acc[mi][ni] = __builtin_amdgcn_mfma_f32_16x16x32_bf16(
              afr[mi], bfr[ni], acc[mi][ni], 0, 0, 0);
    }
    asm volatile("" ::: "memory");
    __builtin_amdgcn_s_barrier();  // all waves done reading buf[cur]
  }

  const int crow0 = brow + wm * WM, ccol0 = bcol + wn * WN;
#pragma unroll
  for (int mi = 0; mi < MF; ++mi) {
    const int row0 = crow0 + mi * 16 + (lane >> 4) * 4;
    const float d0 = dis[row0], d1 = dis[row0 + 1], d2 = dis[row0 + 2],
                d3 = dis[row0 + 3];
#pragma unroll
    for (int ni = 0; ni < NF; ++ni) {
      const int col = ccol0 + ni * 16 + l15;
      f32x4 a = acc[mi][ni];
      if constexpr (EPI == 0) {
        ushort4v o = {f2b(d0 * a.x), f2b(d1 * a.y), f2b(d2 * a.z),
                      f2b(d3 * a.w)};
        *reinterpret_cast<ushort4v*>(outb + (size_t)col * M + row0) = o;
      } else if constexpr (EPI == 1) {
        const float bb = bias[col];
        float v0 = d0 * a.x + bb; v0 = v0 > 0.f ? v0 : 0.f;
        float v1 = d1 * a.y + bb; v1 = v1 > 0.f ? v1 : 0.f;
        float v2 = d2 * a.z + bb; v2 = v2 > 0.f ? v2 : 0.f;
        float v3 = d3 * a.w + bb; v3 = v3 > 0.f ? v3 : 0.f;
        outb[(size_t)(row0 + 0) * N + col] = f2b(v0);
        outb[(size_t)(row0 + 1) * N + col] = f2b(v1);
        outb[(size_t)(row0 + 2) * N + col] = f2b(v2);
        outb[(size_t)(row0 + 3) * N + col] = f2b(v3);
      } else {
        const float bb = bias[col];
        outf[(size_t)(row0 + 0) * N + col] = d0 * a.x + bb;
        outf[(size_t)(row0 + 1) * N + col] = d1 * a.y + bb;
        outf[(size_t)(row0 + 2) * N + col] = d2 * a.z + bb;
        outf[(size_t)(row0 + 3) * N + col] = d3 * a.w + bb;
      }
    }
  }
}

// ---------------------------------------------------------------------------
extern "C" void kernel_launch(void* const* d_in, const int* in_sizes, int n_in,
                              void* d_out, int out_size, void* d_ws,
                              size_t ws_size, hipStream_t stream) {
  const float* A  = (const float*)d_in[0];
  const float* S  = (const float*)d_in[1];
  const float* x  = (const float*)d_in[2];
  const float* W1 = (const float*)d_in[3];
  const float* b1 = (const float*)d_in[4];
  const float* W2 = (const float*)d_in[5];
  const float* b2 = (const float*)d_in[6];
  float* out = (float*)d_out;

  char* ws = (char*)d_ws;
  unsigned short* At  = (unsigned short*)(ws);                // 128 MB
  unsigned short* xb  = (unsigned short*)(ws + 134217728);    // 8 MB
  unsigned short* M1T = (unsigned short*)(ws + 142606336);    // 4 MB [256][8192]
  unsigned short* hb  = (unsigned short*)(ws + 146800640);    // 4 MB [8192][256]
  unsigned short* M2T = (unsigned short*)(ws + 150994944);    // 2 MB [128][8192]
  unsigned short* W1T = (unsigned short*)(ws + 153092096);    // 256 KB [256][512]
  unsigned short* W2T = (unsigned short*)(ws + 153354240);    // 64 KB [128][256]
  float* dis          = (float*)(ws + 153419776);             // 32 KB

  dim3 blk(256);

  // 1. degree + bf16 conversion of A_tilde
  k_degree_convert<<<8192, blk, 0, stream>>>(A, S, At, dis);
  // 2. operand conversions
  k_conv_bf16<<<4096, blk, 0, stream>>>(x, xb, 4194304 / 4);
  k_convT<<<512, blk, 0, stream>>>(W1, W1T, 512, 256);
  k_convT<<<128, blk, 0, stream>>>(W2, W2T, 256, 128);
  // 3. M1^T = (dis ⊙ (x @ W1))^T              [256][8192]
  k_gemm_bt<128, 64, 0><<<dim3(64, 4), blk, 0, stream>>>(
      xb, W1T, 8192, 256, 512, dis, nullptr, nullptr, M1T);
  // 4. h = relu(dis ⊙ (At @ M1) + b1)         [8192][256] bf16
  k_gemm_bt<128, 64, 1><<<dim3(64, 4), blk, 0, stream>>>(
      At, M1T, 8192, 256, 8192, dis, b1, nullptr, hb);
  // 5. M2^T = (dis ⊙ (h @ W2))^T              [128][8192]
  k_gemm_bt<64, 64, 0><<<dim3(128, 2), blk, 0, stream>>>(
      hb, W2T, 8192, 128, 256, dis, nullptr, nullptr, M2T);
  // 6. out = dis ⊙ (At @ M2) + b2             [8192][128] f32
  k_gemm_bt<64, 64, 2><<<dim3(128, 2), blk, 0, stream>>>(
      At, M2T, 8192, 128, 8192, dis, b2, out, nullptr);
}

// Round 3
// 248.489 us; speedup vs baseline: 1.6071x; 1.3443x over previous
//
#include <hip/hip_runtime.h>

#define EPS 1e-8f
#define BETA 0.8f

typedef __attribute__((ext_vector_type(8))) short bf16x8;
typedef __attribute__((ext_vector_type(4))) float f32x4;
typedef __attribute__((ext_vector_type(4))) float float4v;
typedef __attribute__((ext_vector_type(4))) unsigned short ushort4v;

__device__ __forceinline__ unsigned short f2b(float f) {
  unsigned int u = __builtin_bit_cast(unsigned int, f);
  u += 0x7fffu + ((u >> 16) & 1u);
  return (unsigned short)(u >> 16);
}

// ---------------------------------------------------------------------------
// K1: At(bf16) = A + 0.8*S ; dis[row] = 1/sqrt(rowsum + EPS)
// One block per row. All 16 float4 loads issued before any compute (MLP).
// Nontemporal reads: A,S are read-once; keep L3 for At.
// ---------------------------------------------------------------------------
__global__ __launch_bounds__(256) void k_degree_convert(
    const float* __restrict__ A, const float* __restrict__ S,
    unsigned short* __restrict__ At, float* __restrict__ dis) {
  const int row = blockIdx.x;
  const int tid = threadIdx.x;
  const size_t base = (size_t)row * 8192;
  float4v a[8], s[8];
#pragma unroll
  for (int i = 0; i < 8; ++i) {
    const int c = i * 1024 + tid * 4;
    a[i] = __builtin_nontemporal_load(
        reinterpret_cast<const float4v*>(A + base + c));
    s[i] = __builtin_nontemporal_load(
        reinterpret_cast<const float4v*>(S + base + c));
  }
  float sum = 0.f;
#pragma unroll
  for (int i = 0; i < 8; ++i) {
    const int c = i * 1024 + tid * 4;
    float v0 = a[i].x + BETA * s[i].x;
    float v1 = a[i].y + BETA * s[i].y;
    float v2 = a[i].z + BETA * s[i].z;
    float v3 = a[i].w + BETA * s[i].w;
    sum += (v0 + v1) + (v2 + v3);
    ushort4v o = {f2b(v0), f2b(v1), f2b(v2), f2b(v3)};
    *reinterpret_cast<ushort4v*>(At + base + c) = o;
  }
#pragma unroll
  for (int off = 32; off > 0; off >>= 1) sum += __shfl_xor(sum, off, 64);
  __shared__ float wsum[4];
  if ((tid & 63) == 0) wsum[tid >> 6] = sum;
  __syncthreads();
  if (tid == 0) {
    float d = ((wsum[0] + wsum[1]) + (wsum[2] + wsum[3])) + EPS;
    dis[row] = (d > 0.f) ? 1.0f / sqrtf(d) : 0.f;
  }
}

// ---------------------------------------------------------------------------
__global__ __launch_bounds__(256) void k_conv_bf16(
    const float* __restrict__ in, unsigned short* __restrict__ out, int n4) {
  int idx = blockIdx.x * 256 + threadIdx.x;
  if (idx >= n4) return;
  float4v v = reinterpret_cast<const float4v*>(in)[idx];
  ushort4v o = {f2b(v.x), f2b(v.y), f2b(v.z), f2b(v.w)};
  reinterpret_cast<ushort4v*>(out)[idx] = o;
}

__global__ __launch_bounds__(256) void k_convT(
    const float* __restrict__ W, unsigned short* __restrict__ WT, int R, int C) {
  int idx = blockIdx.x * 256 + threadIdx.x;
  if (idx >= R * C) return;
  int r = idx / C, c = idx - r * C;
  WT[c * R + r] = f2b(W[idx]);
}

// ---------------------------------------------------------------------------
// C = A[M][Kstride](bf16) @ BT[N][Kstride](bf16)^T over a K-chunk.
// Double-buffered LDS, counted vmcnt, raw s_barrier. blockIdx.z = K-split idx.
// EPI 0: outb[col*M+row]=bf16(dis[row]*acc)      (transposed, full-K only)
// EPI 1: outb[row*N+col]=bf16(relu(dis*acc+b))   (full-K only)
// EPI 2: outf[row*N+col]=dis*acc+b               (full-K only)
// EPI 3: outf[z*M*N + row*N+col]=acc             (f32 partial, split-K)
// ---------------------------------------------------------------------------
template <int BM, int BN, int EPI>
__global__ __launch_bounds__(256) void k_gemm_bt(
    const unsigned short* __restrict__ Ag,   // [M][Kstride]
    const unsigned short* __restrict__ BTg,  // [N][Kstride]
    int M, int N, int Kstride, int Kchunk,
    const float* __restrict__ dis,
    const float* __restrict__ bias,
    float* __restrict__ outf,
    unsigned short* __restrict__ outb) {
  constexpr int WM = BM / 2, WN = BN / 2;
  constexpr int MF = WM / 16, NF = WN / 16;
  constexpr int NLOADS = BM / 32 + BN / 32;
  __shared__ unsigned short Als[2][BM][64];
  __shared__ unsigned short Bls[2][BN][64];
  const int tid = threadIdx.x;
  const int lane = tid & 63;
  const int wm = (tid >> 6) >> 1, wn = (tid >> 6) & 1;
  const int brow = blockIdx.x * BM, bcol = blockIdx.y * BN;
  const int kbase = blockIdx.z * Kchunk;
  const int ar = tid >> 3;
  const int ac = (tid & 7) * 8;
  const int l15 = lane & 15, lk = (lane >> 4) * 8;

  f32x4 acc[MF][NF];
#pragma unroll
  for (int i = 0; i < MF; ++i)
#pragma unroll
    for (int j = 0; j < NF; ++j) acc[i][j] = (f32x4){0.f, 0.f, 0.f, 0.f};

  auto stage = [&](int buf, int k0) {
#pragma unroll
    for (int i = 0; i < BM / 32; ++i) {
      const unsigned short* g =
          Ag + (size_t)(brow + i * 32 + ar) * Kstride + k0 + ac;
      __builtin_amdgcn_global_load_lds(
          (const __attribute__((address_space(1))) void*)g,
          (__attribute__((address_space(3))) void*)&Als[buf][i * 32 + ar][ac],
          16, 0, 0);
    }
#pragma unroll
    for (int i = 0; i < BN / 32; ++i) {
      const unsigned short* g =
          BTg + (size_t)(bcol + i * 32 + ar) * Kstride + k0 + ac;
      __builtin_amdgcn_global_load_lds(
          (const __attribute__((address_space(1))) void*)g,
          (__attribute__((address_space(3))) void*)&Bls[buf][i * 32 + ar][ac],
          16, 0, 0);
    }
  };

  const int nsteps = Kchunk / 64;
  stage(0, kbase);
  for (int t = 0; t < nsteps; ++t) {
    const int cur = t & 1;
    if (t + 1 < nsteps) {
      stage(cur ^ 1, kbase + (t + 1) * 64);
      asm volatile("s_waitcnt vmcnt(%0)" ::"n"(NLOADS));
    } else {
      asm volatile("s_waitcnt vmcnt(0)");
    }
    __builtin_amdgcn_s_barrier();
    asm volatile("" ::: "memory");
#pragma unroll
    for (int kk = 0; kk < 2; ++kk) {
      bf16x8 afr[MF], bfr[NF];
#pragma unroll
      for (int mi = 0; mi < MF; ++mi)
        afr[mi] = *reinterpret_cast<const bf16x8*>(
            &Als[cur][wm * WM + mi * 16 + l15][kk * 32 + lk]);
#pragma unroll
      for (int ni = 0; ni < NF; ++ni)
        bfr[ni] = *reinterpret_cast<const bf16x8*>(
            &Bls[cur][wn * WN + ni * 16 + l15][kk * 32 + lk]);
#pragma unroll
      for (int mi = 0; mi < MF; ++mi)
#pragma unroll
        for (int ni = 0; ni < NF; ++ni)
          acc[mi][ni] = __builtin_amdgcn_mfma_f32_16x16x32_bf16(
              afr[mi], bfr[ni], acc[mi][ni], 0, 0, 0);
    }
    asm volatile("" ::: "memory");
    __builtin_amdgcn_s_barrier();
  }

  const int crow0 = brow + wm * WM, ccol0 = bcol + wn * WN;
#pragma unroll
  for (int mi = 0; mi < MF; ++mi) {
    const int row0 = crow0 + mi * 16 + (lane >> 4) * 4;
    float d0 = 1.f, d1 = 1.f, d2 = 1.f, d3 = 1.f;
    if constexpr (EPI != 3) {
      d0 = dis[row0]; d1 = dis[row0 + 1]; d2 = dis[row0 + 2]; d3 = dis[row0 + 3];
    }
#pragma unroll
    for (int ni = 0; ni < NF; ++ni) {
      const int col = ccol0 + ni * 16 + l15;
      f32x4 a = acc[mi][ni];
      if constexpr (EPI == 0) {
        ushort4v o = {f2b(d0 * a.x), f2b(d1 * a.y), f2b(d2 * a.z),
                      f2b(d3 * a.w)};
        *reinterpret_cast<ushort4v*>(outb + (size_t)col * M + row0) = o;
      } else if constexpr (EPI == 1) {
        const float bb = bias[col];
        float v0 = d0 * a.x + bb; v0 = v0 > 0.f ? v0 : 0.f;
        float v1 = d1 * a.y + bb; v1 = v1 > 0.f ? v1 : 0.f;
        float v2 = d2 * a.z + bb; v2 = v2 > 0.f ? v2 : 0.f;
        float v3 = d3 * a.w + bb; v3 = v3 > 0.f ? v3 : 0.f;
        outb[(size_t)(row0 + 0) * N + col] = f2b(v0);
        outb[(size_t)(row0 + 1) * N + col] = f2b(v1);
        outb[(size_t)(row0 + 2) * N + col] = f2b(v2);
        outb[(size_t)(row0 + 3) * N + col] = f2b(v3);
      } else if constexpr (EPI == 2) {
        const float bb = bias[col];
        outf[(size_t)(row0 + 0) * N + col] = d0 * a.x + bb;
        outf[(size_t)(row0 + 1) * N + col] = d1 * a.y + bb;
        outf[(size_t)(row0 + 2) * N + col] = d2 * a.z + bb;
        outf[(size_t)(row0 + 3) * N + col] = d3 * a.w + bb;
      } else {
        float* P = outf + (size_t)blockIdx.z * M * N;
        P[(size_t)(row0 + 0) * N + col] = a.x;
        P[(size_t)(row0 + 1) * N + col] = a.y;
        P[(size_t)(row0 + 2) * N + col] = a.z;
        P[(size_t)(row0 + 3) * N + col] = a.w;
      }
    }
  }
}

// ---------------------------------------------------------------------------
// Split-K reduction epilogues. Each thread: 4 consecutive cols.
// MODE 0: hb = bf16(relu(dis*sum + b))   MODE 1: outf = dis*sum + b
// ---------------------------------------------------------------------------
template <int MODE>
__global__ __launch_bounds__(256) void k_reduce4(
    const float* __restrict__ P, int M, int N,
    const float* __restrict__ dis, const float* __restrict__ bias,
    unsigned short* __restrict__ outb, float* __restrict__ outf) {
  const int idx = blockIdx.x * 256 + threadIdx.x;  // one per 4 cols
  const int row = idx / (N / 4);
  const int c0 = (idx - row * (N / 4)) * 4;
  const size_t off = (size_t)row * N + c0;
  const size_t ps = (size_t)M * N;
  float4v v0 = *reinterpret_cast<const float4v*>(P + off);
  float4v v1 = *reinterpret_cast<const float4v*>(P + ps + off);
  float4v v2 = *reinterpret_cast<const float4v*>(P + 2 * ps + off);
  float4v v3 = *reinterpret_cast<const float4v*>(P + 3 * ps + off);
  const float d = dis[row];
  float4v bb = *reinterpret_cast<const float4v*>(bias + c0);
  float r0 = d * ((v0.x + v1.x) + (v2.x + v3.x)) + bb.x;
  float r1 = d * ((v0.y + v1.y) + (v2.y + v3.y)) + bb.y;
  float r2 = d * ((v0.z + v1.z) + (v2.z + v3.z)) + bb.z;
  float r3 = d * ((v0.w + v1.w) + (v2.w + v3.w)) + bb.w;
  if constexpr (MODE == 0) {
    r0 = r0 > 0.f ? r0 : 0.f;
    r1 = r1 > 0.f ? r1 : 0.f;
    r2 = r2 > 0.f ? r2 : 0.f;
    r3 = r3 > 0.f ? r3 : 0.f;
    ushort4v o = {f2b(r0), f2b(r1), f2b(r2), f2b(r3)};
    *reinterpret_cast<ushort4v*>(outb + off) = o;
  } else {
    float4v o = {r0, r1, r2, r3};
    *reinterpret_cast<float4v*>(outf + off) = o;
  }
}

// ---------------------------------------------------------------------------
extern "C" void kernel_launch(void* const* d_in, const int* in_sizes, int n_in,
                              void* d_out, int out_size, void* d_ws,
                              size_t ws_size, hipStream_t stream) {
  const float* A  = (const float*)d_in[0];
  const float* S  = (const float*)d_in[1];
  const float* x  = (const float*)d_in[2];
  const float* W1 = (const float*)d_in[3];
  const float* b1 = (const float*)d_in[4];
  const float* W2 = (const float*)d_in[5];
  const float* b2 = (const float*)d_in[6];
  float* out = (float*)d_out;

  char* ws = (char*)d_ws;
  dim3 blk(256);

  // ---- split-K layout (with overlays) ----
  // At 0..128M | xb 128M..136M (M2T overlays after GEMM3)
  // M1T 136M..140M (hb overlays after GEMM4) | P 140M..172M (P4 then P6)
  // W1T/W2T/dis tail. NEED ~= 180.7 MB
  const size_t O_At = 0, O_xb = 134217728, O_M1T = 142606336,
               O_P = 146800640, O_W1T = 180355072, O_W2T = 180617216,
               O_dis = 180682752, NEED = 180715520;

  if (ws_size >= NEED) {
    unsigned short* At  = (unsigned short*)(ws + O_At);
    unsigned short* xb  = (unsigned short*)(ws + O_xb);
    unsigned short* M1T = (unsigned short*)(ws + O_M1T);
    float*          P   = (float*)(ws + O_P);
    unsigned short* hb  = (unsigned short*)(ws + O_M1T);  // overlay M1T
    unsigned short* M2T = (unsigned short*)(ws + O_xb);   // overlay xb
    unsigned short* W1T = (unsigned short*)(ws + O_W1T);
    unsigned short* W2T = (unsigned short*)(ws + O_W2T);
    float*          dis = (float*)(ws + O_dis);

    k_degree_convert<<<8192, blk, 0, stream>>>(A, S, At, dis);
    k_conv_bf16<<<4096, blk, 0, stream>>>(x, xb, 4194304 / 4);
    k_convT<<<512, blk, 0, stream>>>(W1, W1T, 512, 256);
    k_convT<<<128, blk, 0, stream>>>(W2, W2T, 256, 128);
    // M1^T = (dis ⊙ (x @ W1))^T   [256][8192]
    k_gemm_bt<128, 64, 0><<<dim3(64, 4), blk, 0, stream>>>(
        xb, W1T, 8192, 256, 512, 512, dis, nullptr, nullptr, M1T);
    // P4[z] = (At @ M1)_z  split-K=4
    k_gemm_bt<128, 64, 3><<<dim3(64, 4, 4), blk, 0, stream>>>(
        At, M1T, 8192, 256, 8192, 2048, nullptr, nullptr, P, nullptr);
    // h = relu(dis*sum + b1)  bf16
    k_reduce4<0><<<2048, blk, 0, stream>>>(P, 8192, 256, dis, b1, hb, nullptr);
    // M2^T = (dis ⊙ (h @ W2))^T   [128][8192]
    k_gemm_bt<64, 64, 0><<<dim3(128, 2), blk, 0, stream>>>(
        hb, W2T, 8192, 128, 256, 256, dis, nullptr, nullptr, M2T);
    // P6[z] = (At @ M2)_z  split-K=4
    k_gemm_bt<64, 64, 3><<<dim3(128, 2, 4), blk, 0, stream>>>(
        At, M2T, 8192, 128, 8192, 2048, nullptr, nullptr, P, nullptr);
    // out = dis*sum + b2  f32
    k_reduce4<1><<<1024, blk, 0, stream>>>(P, 8192, 128, dis, b2, nullptr, out);
  } else {
    // fallback: round-2 non-split path
    unsigned short* At  = (unsigned short*)(ws);
    unsigned short* xb  = (unsigned short*)(ws + 134217728);
    unsigned short* M1T = (unsigned short*)(ws + 142606336);
    unsigned short* hb  = (unsigned short*)(ws + 146800640);
    unsigned short* M2T = (unsigned short*)(ws + 150994944);
    unsigned short* W1T = (unsigned short*)(ws + 153092096);
    unsigned short* W2T = (unsigned short*)(ws + 153354240);
    float* dis          = (float*)(ws + 153419776);

    k_degree_convert<<<8192, blk, 0, stream>>>(A, S, At, dis);
    k_conv_bf16<<<4096, blk, 0, stream>>>(x, xb, 4194304 / 4);
    k_convT<<<512, blk, 0, stream>>>(W1, W1T, 512, 256);
    k_convT<<<128, blk, 0, stream>>>(W2, W2T, 256, 128);
    k_gemm_bt<128, 64, 0><<<dim3(64, 4), blk, 0, stream>>>(
        xb, W1T, 8192, 256, 512, 512, dis, nullptr, nullptr, M1T);
    k_gemm_bt<128, 64, 1><<<dim3(64, 4), blk, 0, stream>>>(
        At, M1T, 8192, 256, 8192, 8192, dis, b1, nullptr, hb);
    k_gemm_bt<64, 64, 0><<<dim3(128, 2), blk, 0, stream>>>(
        hb, W2T, 8192, 128, 256, 256, dis, nullptr, nullptr, M2T);
    k_gemm_bt<64, 64, 2><<<dim3(128, 2), blk, 0, stream>>>(
        At, M2T, 8192, 128, 8192, 8192, dis, b2, out, nullptr);
  }
}

// Round 4
// 233.415 us; speedup vs baseline: 1.7109x; 1.0646x over previous
//
#include <hip/hip_runtime.h>

#define EPS 1e-8f
#define BETA 0.8f

typedef __attribute__((ext_vector_type(8))) short bf16x8;
typedef __attribute__((ext_vector_type(4))) float f32x4;
typedef __attribute__((ext_vector_type(4))) float float4v;
typedef __attribute__((ext_vector_type(4))) unsigned short ushort4v;

__device__ __forceinline__ unsigned short f2b(float f) {
  unsigned int u = __builtin_bit_cast(unsigned int, f);
  u += 0x7fffu + ((u >> 16) & 1u);
  return (unsigned short)(u >> 16);
}

// ---------------------------------------------------------------------------
// K1: At(bf16) = A + 0.8*S ; dis[row] = 1/sqrt(rowsum + EPS)
// ---------------------------------------------------------------------------
__global__ __launch_bounds__(256) void k_degree_convert(
    const float* __restrict__ A, const float* __restrict__ S,
    unsigned short* __restrict__ At, float* __restrict__ dis) {
  const int row = blockIdx.x;
  const int tid = threadIdx.x;
  const size_t base = (size_t)row * 8192;
  float4v a[8], s[8];
#pragma unroll
  for (int i = 0; i < 8; ++i) {
    const int c = i * 1024 + tid * 4;
    a[i] = __builtin_nontemporal_load(
        reinterpret_cast<const float4v*>(A + base + c));
    s[i] = __builtin_nontemporal_load(
        reinterpret_cast<const float4v*>(S + base + c));
  }
  float sum = 0.f;
#pragma unroll
  for (int i = 0; i < 8; ++i) {
    const int c = i * 1024 + tid * 4;
    float v0 = a[i].x + BETA * s[i].x;
    float v1 = a[i].y + BETA * s[i].y;
    float v2 = a[i].z + BETA * s[i].z;
    float v3 = a[i].w + BETA * s[i].w;
    sum += (v0 + v1) + (v2 + v3);
    ushort4v o = {f2b(v0), f2b(v1), f2b(v2), f2b(v3)};
    *reinterpret_cast<ushort4v*>(At + base + c) = o;
  }
#pragma unroll
  for (int off = 32; off > 0; off >>= 1) sum += __shfl_xor(sum, off, 64);
  __shared__ float wsum[4];
  if ((tid & 63) == 0) wsum[tid >> 6] = sum;
  __syncthreads();
  if (tid == 0) {
    float d = ((wsum[0] + wsum[1]) + (wsum[2] + wsum[3])) + EPS;
    dis[row] = (d > 0.f) ? 1.0f / sqrtf(d) : 0.f;
  }
}

// ---------------------------------------------------------------------------
__global__ __launch_bounds__(256) void k_conv_bf16(
    const float* __restrict__ in, unsigned short* __restrict__ out, int n4) {
  int idx = blockIdx.x * 256 + threadIdx.x;
  if (idx >= n4) return;
  float4v v = reinterpret_cast<const float4v*>(in)[idx];
  ushort4v o = {f2b(v.x), f2b(v.y), f2b(v.z), f2b(v.w)};
  reinterpret_cast<ushort4v*>(out)[idx] = o;
}

__global__ __launch_bounds__(256) void k_convT(
    const float* __restrict__ W, unsigned short* __restrict__ WT, int R, int C) {
  int idx = blockIdx.x * 256 + threadIdx.x;
  if (idx >= R * C) return;
  int r = idx / C, c = idx - r * C;
  WT[c * R + r] = f2b(W[idx]);
}

// ---------------------------------------------------------------------------
// Small GEMM (4 waves, 128/64 x 64 tile): C = A@BT^T over full K.
// EPI 0: outb[col*M+row]=bf16(dis[row]*acc) transposed
// EPI 1: outb[row*N+col]=bf16(relu(dis*acc+b))
// EPI 2: outf[row*N+col]=dis*acc+b
// ---------------------------------------------------------------------------
template <int BM, int BN, int EPI>
__global__ __launch_bounds__(256) void k_gemm_bt(
    const unsigned short* __restrict__ Ag, const unsigned short* __restrict__ BTg,
    int M, int N, int Kstride, int Kchunk,
    const float* __restrict__ dis, const float* __restrict__ bias,
    float* __restrict__ outf, unsigned short* __restrict__ outb) {
  constexpr int WM = BM / 2, WN = BN / 2;
  constexpr int MF = WM / 16, NF = WN / 16;
  constexpr int NLOADS = BM / 32 + BN / 32;
  __shared__ unsigned short Als[2][BM][64];
  __shared__ unsigned short Bls[2][BN][64];
  const int tid = threadIdx.x;
  const int lane = tid & 63;
  const int wm = (tid >> 6) >> 1, wn = (tid >> 6) & 1;
  const int brow = blockIdx.x * BM, bcol = blockIdx.y * BN;
  const int ar = tid >> 3;
  const int ac = (tid & 7) * 8;
  const int l15 = lane & 15, lk = (lane >> 4) * 8;

  f32x4 acc[MF][NF];
#pragma unroll
  for (int i = 0; i < MF; ++i)
#pragma unroll
    for (int j = 0; j < NF; ++j) acc[i][j] = (f32x4){0.f, 0.f, 0.f, 0.f};

  auto stage = [&](int buf, int k0) {
#pragma unroll
    for (int i = 0; i < BM / 32; ++i) {
      const unsigned short* g =
          Ag + (size_t)(brow + i * 32 + ar) * Kstride + k0 + ac;
      __builtin_amdgcn_global_load_lds(
          (const __attribute__((address_space(1))) void*)g,
          (__attribute__((address_space(3))) void*)&Als[buf][i * 32 + ar][ac],
          16, 0, 0);
    }
#pragma unroll
    for (int i = 0; i < BN / 32; ++i) {
      const unsigned short* g =
          BTg + (size_t)(bcol + i * 32 + ar) * Kstride + k0 + ac;
      __builtin_amdgcn_global_load_lds(
          (const __attribute__((address_space(1))) void*)g,
          (__attribute__((address_space(3))) void*)&Bls[buf][i * 32 + ar][ac],
          16, 0, 0);
    }
  };

  const int nsteps = Kchunk / 64;
  stage(0, 0);
  for (int t = 0; t < nsteps; ++t) {
    const int cur = t & 1;
    if (t + 1 < nsteps) {
      stage(cur ^ 1, (t + 1) * 64);
      asm volatile("s_waitcnt vmcnt(%0)" ::"n"(NLOADS));
    } else {
      asm volatile("s_waitcnt vmcnt(0)");
    }
    __builtin_amdgcn_s_barrier();
    asm volatile("" ::: "memory");
#pragma unroll
    for (int kk = 0; kk < 2; ++kk) {
      bf16x8 afr[MF], bfr[NF];
#pragma unroll
      for (int mi = 0; mi < MF; ++mi)
        afr[mi] = *reinterpret_cast<const bf16x8*>(
            &Als[cur][wm * WM + mi * 16 + l15][kk * 32 + lk]);
#pragma unroll
      for (int ni = 0; ni < NF; ++ni)
        bfr[ni] = *reinterpret_cast<const bf16x8*>(
            &Bls[cur][wn * WN + ni * 16 + l15][kk * 32 + lk]);
#pragma unroll
      for (int mi = 0; mi < MF; ++mi)
#pragma unroll
        for (int ni = 0; ni < NF; ++ni)
          acc[mi][ni] = __builtin_amdgcn_mfma_f32_16x16x32_bf16(
              afr[mi], bfr[ni], acc[mi][ni], 0, 0, 0);
    }
    asm volatile("" ::: "memory");
    __builtin_amdgcn_s_barrier();
  }

  const int crow0 = brow + wm * WM, ccol0 = bcol + wn * WN;
#pragma unroll
  for (int mi = 0; mi < MF; ++mi) {
    const int row0 = crow0 + mi * 16 + (lane >> 4) * 4;
    const float d0 = dis[row0], d1 = dis[row0 + 1], d2 = dis[row0 + 2],
                d3 = dis[row0 + 3];
#pragma unroll
    for (int ni = 0; ni < NF; ++ni) {
      const int col = ccol0 + ni * 16 + l15;
      f32x4 a = acc[mi][ni];
      if constexpr (EPI == 0) {
        ushort4v o = {f2b(d0 * a.x), f2b(d1 * a.y), f2b(d2 * a.z),
                      f2b(d3 * a.w)};
        *reinterpret_cast<ushort4v*>(outb + (size_t)col * M + row0) = o;
      } else if constexpr (EPI == 1) {
        const float bb = bias[col];
        float v0 = d0 * a.x + bb; v0 = v0 > 0.f ? v0 : 0.f;
        float v1 = d1 * a.y + bb; v1 = v1 > 0.f ? v1 : 0.f;
        float v2 = d2 * a.z + bb; v2 = v2 > 0.f ? v2 : 0.f;
        float v3 = d3 * a.w + bb; v3 = v3 > 0.f ? v3 : 0.f;
        outb[(size_t)(row0 + 0) * N + col] = f2b(v0);
        outb[(size_t)(row0 + 1) * N + col] = f2b(v1);
        outb[(size_t)(row0 + 2) * N + col] = f2b(v2);
        outb[(size_t)(row0 + 3) * N + col] = f2b(v3);
      } else {
        const float bb = bias[col];
        outf[(size_t)(row0 + 0) * N + col] = d0 * a.x + bb;
        outf[(size_t)(row0 + 1) * N + col] = d1 * a.y + bb;
        outf[(size_t)(row0 + 2) * N + col] = d2 * a.z + bb;
        outf[(size_t)(row0 + 3) * N + col] = d3 * a.w + bb;
      }
    }
  }
}

// ---------------------------------------------------------------------------
// Big split-K GEMM: 256x64 tile, 512 threads (8 waves, 4Mx2N), 2 blocks/CU.
// P[z*M*N + row*N + col] = partial f32 accumulation over K-chunk.
// ---------------------------------------------------------------------------
__global__ __launch_bounds__(512, 4) void k_gemm_big(
    const unsigned short* __restrict__ Ag,   // [M][Kstride]
    const unsigned short* __restrict__ BTg,  // [N][Kstride]
    int M, int N, int Kstride, int Kchunk,
    float* __restrict__ P) {
  constexpr int BM = 256, BN = 64;
  constexpr int MF = 4, NF = 2;       // wave tile 64x32
  constexpr int NLOADS = 5;           // 4 A-slabs + 1 B-slab per thread
  __shared__ unsigned short Als[2][BM][64];
  __shared__ unsigned short Bls[2][BN][64];
  const int tid = threadIdx.x;
  const int lane = tid & 63;
  const int wid = tid >> 6;           // 0..7
  const int wm = wid >> 1, wn = wid & 1;
  const int brow = blockIdx.x * BM, bcol = blockIdx.y * BN;
  const int kbase = blockIdx.z * Kchunk;
  const int ar = tid >> 3;            // 0..63
  const int ac = (tid & 7) * 8;
  const int l15 = lane & 15, lk = (lane >> 4) * 8;

  f32x4 acc[MF][NF];
#pragma unroll
  for (int i = 0; i < MF; ++i)
#pragma unroll
    for (int j = 0; j < NF; ++j) acc[i][j] = (f32x4){0.f, 0.f, 0.f, 0.f};

  auto stage = [&](int buf, int k0) {
#pragma unroll
    for (int i = 0; i < 4; ++i) {
      const unsigned short* g =
          Ag + (size_t)(brow + i * 64 + ar) * Kstride + k0 + ac;
      __builtin_amdgcn_global_load_lds(
          (const __attribute__((address_space(1))) void*)g,
          (__attribute__((address_space(3))) void*)&Als[buf][i * 64 + ar][ac],
          16, 0, 0);
    }
    {
      const unsigned short* g = BTg + (size_t)(bcol + ar) * Kstride + k0 + ac;
      __builtin_amdgcn_global_load_lds(
          (const __attribute__((address_space(1))) void*)g,
          (__attribute__((address_space(3))) void*)&Bls[buf][ar][ac], 16, 0, 0);
    }
  };

  const int nsteps = Kchunk / 64;
  stage(0, kbase);
  for (int t = 0; t < nsteps; ++t) {
    const int cur = t & 1;
    if (t + 1 < nsteps) {
      stage(cur ^ 1, kbase + (t + 1) * 64);
      asm volatile("s_waitcnt vmcnt(%0)" ::"n"(NLOADS));
    } else {
      asm volatile("s_waitcnt vmcnt(0)");
    }
    __builtin_amdgcn_s_barrier();
    asm volatile("" ::: "memory");
#pragma unroll
    for (int kk = 0; kk < 2; ++kk) {
      bf16x8 afr[MF], bfr[NF];
#pragma unroll
      for (int mi = 0; mi < MF; ++mi)
        afr[mi] = *reinterpret_cast<const bf16x8*>(
            &Als[cur][wm * 64 + mi * 16 + l15][kk * 32 + lk]);
#pragma unroll
      for (int ni = 0; ni < NF; ++ni)
        bfr[ni] = *reinterpret_cast<const bf16x8*>(
            &Bls[cur][wn * 32 + ni * 16 + l15][kk * 32 + lk]);
#pragma unroll
      for (int mi = 0; mi < MF; ++mi)
#pragma unroll
        for (int ni = 0; ni < NF; ++ni)
          acc[mi][ni] = __builtin_amdgcn_mfma_f32_16x16x32_bf16(
              afr[mi], bfr[ni], acc[mi][ni], 0, 0, 0);
    }
    asm volatile("" ::: "memory");
    __builtin_amdgcn_s_barrier();
  }

  float* Pz = P + (size_t)blockIdx.z * M * N;
  const int crow0 = brow + wm * 64, ccol0 = bcol + wn * 32;
#pragma unroll
  for (int mi = 0; mi < MF; ++mi) {
    const int row0 = crow0 + mi * 16 + (lane >> 4) * 4;
#pragma unroll
    for (int ni = 0; ni < NF; ++ni) {
      const int col = ccol0 + ni * 16 + l15;
      f32x4 a = acc[mi][ni];
      Pz[(size_t)(row0 + 0) * N + col] = a.x;
      Pz[(size_t)(row0 + 1) * N + col] = a.y;
      Pz[(size_t)(row0 + 2) * N + col] = a.z;
      Pz[(size_t)(row0 + 3) * N + col] = a.w;
    }
  }
}

// ---------------------------------------------------------------------------
// Split-K reduction. NS partials. MODE 0: bf16 relu(dis*sum+b). 1: f32.
// ---------------------------------------------------------------------------
template <int MODE, int NS>
__global__ __launch_bounds__(256) void k_reduceN(
    const float* __restrict__ P, int M, int N,
    const float* __restrict__ dis, const float* __restrict__ bias,
    unsigned short* __restrict__ outb, float* __restrict__ outf) {
  const int idx = blockIdx.x * 256 + threadIdx.x;
  const int row = idx / (N / 4);
  const int c0 = (idx - row * (N / 4)) * 4;
  const size_t off = (size_t)row * N + c0;
  const size_t ps = (size_t)M * N;
  float r0 = 0.f, r1 = 0.f, r2 = 0.f, r3 = 0.f;
#pragma unroll
  for (int z = 0; z < NS; ++z) {
    float4v v = *reinterpret_cast<const float4v*>(P + z * ps + off);
    r0 += v.x; r1 += v.y; r2 += v.z; r3 += v.w;
  }
  const float d = dis[row];
  float4v bb = *reinterpret_cast<const float4v*>(bias + c0);
  r0 = d * r0 + bb.x; r1 = d * r1 + bb.y;
  r2 = d * r2 + bb.z; r3 = d * r3 + bb.w;
  if constexpr (MODE == 0) {
    r0 = r0 > 0.f ? r0 : 0.f;
    r1 = r1 > 0.f ? r1 : 0.f;
    r2 = r2 > 0.f ? r2 : 0.f;
    r3 = r3 > 0.f ? r3 : 0.f;
    ushort4v o = {f2b(r0), f2b(r1), f2b(r2), f2b(r3)};
    *reinterpret_cast<ushort4v*>(outb + off) = o;
  } else {
    float4v o = {r0, r1, r2, r3};
    *reinterpret_cast<float4v*>(outf + off) = o;
  }
}

// ---------------------------------------------------------------------------
extern "C" void kernel_launch(void* const* d_in, const int* in_sizes, int n_in,
                              void* d_out, int out_size, void* d_ws,
                              size_t ws_size, hipStream_t stream) {
  const float* A  = (const float*)d_in[0];
  const float* S  = (const float*)d_in[1];
  const float* x  = (const float*)d_in[2];
  const float* W1 = (const float*)d_in[3];
  const float* b1 = (const float*)d_in[4];
  const float* W2 = (const float*)d_in[5];
  const float* b2 = (const float*)d_in[6];
  float* out = (float*)d_out;

  char* ws = (char*)d_ws;
  dim3 blk(256);

  const size_t O_At = 0, O_xb = 134217728, O_M1T = 142606336,
               O_P = 146800640, O_W1T = 180355072, O_W2T = 180617216,
               O_dis = 180682752, NEED = 180715520;

  if (ws_size >= NEED) {
    unsigned short* At  = (unsigned short*)(ws + O_At);
    unsigned short* xb  = (unsigned short*)(ws + O_xb);
    unsigned short* M1T = (unsigned short*)(ws + O_M1T);
    float*          P   = (float*)(ws + O_P);
    unsigned short* hb  = (unsigned short*)(ws + O_M1T);  // overlay M1T
    unsigned short* M2T = (unsigned short*)(ws + O_xb);   // overlay xb
    unsigned short* W1T = (unsigned short*)(ws + O_W1T);
    unsigned short* W2T = (unsigned short*)(ws + O_W2T);
    float*          dis = (float*)(ws + O_dis);

    k_degree_convert<<<8192, blk, 0, stream>>>(A, S, At, dis);
    k_conv_bf16<<<4096, blk, 0, stream>>>(x, xb, 4194304 / 4);
    k_convT<<<512, blk, 0, stream>>>(W1, W1T, 512, 256);
    k_convT<<<128, blk, 0, stream>>>(W2, W2T, 256, 128);
    // M1^T = (dis ⊙ (x @ W1))^T   [256][8192]
    k_gemm_bt<128, 64, 0><<<dim3(64, 4), blk, 0, stream>>>(
        xb, W1T, 8192, 256, 512, 512, dis, nullptr, nullptr, M1T);
    // P[z] = (At @ M1)_z   SK=4, 256x64 tile, 2 blocks/CU
    k_gemm_big<<<dim3(32, 4, 4), dim3(512), 0, stream>>>(
        At, M1T, 8192, 256, 8192, 2048, P);
    k_reduceN<0, 4><<<2048, blk, 0, stream>>>(P, 8192, 256, dis, b1, hb,
                                              nullptr);
    // M2^T = (dis ⊙ (h @ W2))^T   [128][8192]
    k_gemm_bt<64, 64, 0><<<dim3(128, 2), blk, 0, stream>>>(
        hb, W2T, 8192, 128, 256, 256, dis, nullptr, nullptr, M2T);
    // P[z] = (At @ M2)_z   SK=8
    k_gemm_big<<<dim3(32, 2, 8), dim3(512), 0, stream>>>(
        At, M2T, 8192, 128, 8192, 1024, P);
    k_reduceN<1, 8><<<1024, blk, 0, stream>>>(P, 8192, 128, dis, b2, nullptr,
                                              out);
  } else {
    unsigned short* At  = (unsigned short*)(ws);
    unsigned short* xb  = (unsigned short*)(ws + 134217728);
    unsigned short* M1T = (unsigned short*)(ws + 142606336);
    unsigned short* hb  = (unsigned short*)(ws + 146800640);
    unsigned short* M2T = (unsigned short*)(ws + 150994944);
    unsigned short* W1T = (unsigned short*)(ws + 153092096);
    unsigned short* W2T = (unsigned short*)(ws + 153354240);
    float* dis          = (float*)(ws + 153419776);

    k_degree_convert<<<8192, blk, 0, stream>>>(A, S, At, dis);
    k_conv_bf16<<<4096, blk, 0, stream>>>(x, xb, 4194304 / 4);
    k_convT<<<512, blk, 0, stream>>>(W1, W1T, 512, 256);
    k_convT<<<128, blk, 0, stream>>>(W2, W2T, 256, 128);
    k_gemm_bt<128, 64, 0><<<dim3(64, 4), blk, 0, stream>>>(
        xb, W1T, 8192, 256, 512, 512, dis, nullptr, nullptr, M1T);
    k_gemm_bt<128, 64, 1><<<dim3(64, 4), blk, 0, stream>>>(
        At, M1T, 8192, 256, 8192, 8192, dis, b1, nullptr, hb);
    k_gemm_bt<64, 64, 0><<<dim3(128, 2), blk, 0, stream>>>(
        hb, W2T, 8192, 128, 256, 256, dis, nullptr, nullptr, M2T);
    k_gemm_bt<64, 64, 2><<<dim3(128, 2), blk, 0, stream>>>(
        At, M2T, 8192, 128, 8192, 8192, dis, b2, out, nullptr);
  }
}